// Round 5
// baseline (374.614 us; speedup 1.0000x reference)
//
#include <hip/hip_runtime.h>

// Problem constants: B=1024, V=64, DIN=256, DOUT=256, fp32 in/out.
#define EPS 1e-5f

typedef __bf16 bf16_t;
typedef bf16_t bf16x4 __attribute__((ext_vector_type(4)));
typedef bf16_t bf16x8 __attribute__((ext_vector_type(8)));
typedef float  floatx4 __attribute__((ext_vector_type(4)));

// Fragment-pack layouts (verified, rounds 1-3):
//   A-frag chunk (mt, ks, lane): A[m = mt*16 + (lane&15)][k = ks*32 + (lane>>4)*8 + j]
//   B-frag chunk (nt, ks, lane): B[k = ks*32 + (lane>>4)*8 + j][n = nt*16 + (lane&15)]
//   C/D: col = lane&15, row = (lane>>4)*4 + reg

#define GLOAD_LDS16(g, l)                                          \
  __builtin_amdgcn_global_load_lds(                                \
      (const __attribute__((address_space(1))) void*)(g),          \
      (__attribute__((address_space(3))) void*)(l), 16, 0, 0)

// ---------------------------------------------------------------------------
// Round-5 structural change: rounds 1-4 showed (total - k1) == 126 +/- 1 us
// while k1 varied 45..69 and every pipe sat <12% busy -> a ~35-40us fixed
// per-dispatch cost dominates (4 dispatches ~= 160us of the 174). Fix: ONE
// dispatch, 4 phases, manual grid barrier between phases.
//   - barrier state in __device__ globals: zero-init at module load,
//     self-resetting (generation counter) across graph replays; no dependence
//     on poisoned workspace; no cooperative-launch-under-capture risk.
//   - co-residency by construction: __launch_bounds__(256,2) + 66.5KB LDS
//     -> 2 blocks/CU; grid = 512 = 2 x 256 CUs exactly.
//   - XCD L2 non-coherence (G16): __threadfence() (agent-scope release,
//     L2 writeback) before arrival; agent-scope acquire loads on exit.
// Phase bodies are identical to the round-4 kernels (k0a/k1/k2/k4), only
// blockIdx remapped, to isolate the fusion effect.
// ---------------------------------------------------------------------------

__device__ unsigned g_count = 0;
__device__ unsigned g_gen = 0;

__device__ __forceinline__ void grid_barrier() {
  __syncthreads();
  if (threadIdx.x == 0) {
    __threadfence();  // agent-scope release: makes this block's writes visible
    unsigned my_gen =
        __hip_atomic_load(&g_gen, __ATOMIC_ACQUIRE, __HIP_MEMORY_SCOPE_AGENT);
    unsigned prev = __hip_atomic_fetch_add(&g_count, 1u, __ATOMIC_ACQ_REL,
                                           __HIP_MEMORY_SCOPE_AGENT);
    if (prev == 511u) {  // last to arrive: reset count, flip generation
      __hip_atomic_store(&g_count, 0u, __ATOMIC_RELAXED,
                         __HIP_MEMORY_SCOPE_AGENT);
      __hip_atomic_fetch_add(&g_gen, 1u, __ATOMIC_RELEASE,
                             __HIP_MEMORY_SCOPE_AGENT);
    } else {
      while (__hip_atomic_load(&g_gen, __ATOMIC_ACQUIRE,
                               __HIP_MEMORY_SCOPE_AGENT) == my_gen)
        __builtin_amdgcn_s_sleep(2);
    }
  }
  __syncthreads();
}

__global__ __launch_bounds__(256, 2) void fused_all(
    const float* __restrict__ feat, const float* __restrict__ adj,
    const float* __restrict__ W, const float* __restrict__ bias,
    const float* __restrict__ gamma, const float* __restrict__ beta,
    float* __restrict__ out, bf16_t* __restrict__ Bp,
    bf16_t* __restrict__ hbuf, float* __restrict__ g_sum,
    float* __restrict__ g_sq, bf16_t* __restrict__ a_bf,
    bf16_t* __restrict__ c_bf, bf16_t* __restrict__ adjB) {
  // Shared arena, phase-aliased. Max user: phase 1 (66560 B) -> 2 blocks/CU.
  __shared__ __attribute__((aligned(16))) char smem[66560];

  int blk = blockIdx.x, tid = threadIdx.x;
  int lane = tid & 63, wave = tid >> 6;
  int r16 = lane & 15, quad = lane >> 4;

  // ======================= Phase 0: pack W / adj / zero stats ==============
  {
    float (*Ls)[260] = (float(*)[260])smem;
    int v = blk >> 3, ks = blk & 7, k0 = ks * 32;
    const float* Wv = W + (size_t)v * 65536;
    #pragma unroll
    for (int it = 0; it < 8; ++it) {
      int idx = it * 256 + tid;
      int row = idx >> 6, c4 = idx & 63;
      *(float4*)&Ls[row][c4 * 4] =
          *(const float4*)(Wv + (size_t)(k0 + row) * 256 + c4 * 4);
    }
    __syncthreads();
    #pragma unroll
    for (int it = 0; it < 4; ++it) {
      int cc = it * 256 + tid;
      int nt = cc >> 6, lanec = cc & 63;
      int n = nt * 16 + (lanec & 15), kq = (lanec >> 4) * 8;
      bf16x8 d;
      #pragma unroll
      for (int j = 0; j < 8; ++j) d[j] = (bf16_t)Ls[kq + j][n];
      *(bf16x8*)(Bp + ((size_t)(v * 16 + nt) * 8 + ks) * 512 + lanec * 8) = d;
    }
    if (blk == 0) {  // adjB = bf16(adj), 64x64
      int base = tid * 16;
      #pragma unroll
      for (int half = 0; half < 2; ++half) {
        float4 f0 = *(const float4*)(adj + base + half * 8);
        float4 f1 = *(const float4*)(adj + base + half * 8 + 4);
        bf16x8 d = {(bf16_t)f0.x, (bf16_t)f0.y, (bf16_t)f0.z, (bf16_t)f0.w,
                    (bf16_t)f1.x, (bf16_t)f1.y, (bf16_t)f1.z, (bf16_t)f1.w};
        *(bf16x8*)(adjB + base + half * 8) = d;
      }
    }
    if (blk == 1) {  // zero g_sum/g_sq (16384 floats each)
      float4 z = {0.f, 0.f, 0.f, 0.f};
      #pragma unroll
      for (int i = 0; i < 16; ++i) {
        *(float4*)(g_sum + (i * 256 + tid) * 4) = z;
        *(float4*)(g_sq + (i * 256 + tid) * 4) = z;
      }
    }
  }
  grid_barrier();

  // ======================= Phase 1: GEMM h = feat@W + b, stats =============
  {
    float* Abuf0 = (float*)smem;              // [128][64] fp32, 32 KB
    float* Abuf1 = (float*)(smem + 32768);    // [128][64] fp32, 32 KB
    float* s_sum = (float*)(smem + 65536);    // 128 f
    float* s_sq  = (float*)(smem + 66048);    // 128 f
    float* AbufP[2] = {Abuf0, Abuf1};

    int wm = wave >> 1, wn = wave & 1;        // 2 (m=b) x 2 (n=o)
    int v = blk & 63, oh = (blk >> 6) & 1;
    int lrow = lane >> 4, slot = lane & 15;

    // B pointers constant across both b-tiles (same v, oh)
    const bf16_t* bpb[4];
    #pragma unroll
    for (int ni = 0; ni < 4; ++ni) {
      int nt = oh * 8 + wn * 4 + ni;
      bpb[ni] = Bp + ((size_t)(v * 16 + nt) * 8) * 512 + lane * 8;
    }
    float bias_r[4];
    #pragma unroll
    for (int ni = 0; ni < 4; ++ni)
      bias_r[ni] = bias[v * 256 + oh * 128 + wn * 64 + ni * 16 + r16];

    for (int t = 0; t < 2; ++t) {
      int b0 = ((blk >> 7) + t * 4) * 128;    // bz 0..3 then 4..7
      const float* fv = feat + (size_t)b0 * 16384 + v * 256;

      __syncthreads();  // prev tile's Cs/LDS reads complete
      if (tid < 128) { s_sum[tid] = 0.f; s_sq[tid] = 0.f; }

      #define STAGE(buf, kh)                                                   \
        {                                                                      \
          _Pragma("unroll")                                                    \
          for (int rr = 0; rr < 8; ++rr) {                                     \
            int row0 = rr * 16 + wave * 4;                                     \
            int row = row0 + lrow;                                             \
            int soff = (slot * 16) ^ ((row & 15) << 4);                        \
            const float* src =                                                 \
                fv + (size_t)row * 16384 + (kh) * 64 + (soff >> 2);            \
            GLOAD_LDS16(src, AbufP[buf] + row0 * 64);                          \
          }                                                                    \
        }

      floatx4 acc[4][4] = {};
      STAGE(0, 0);
      __syncthreads();  // chunk 0 staged; s_sum init visible

      auto lda = [&](int buf, int mi, int ks_loc) -> bf16x8 {
        int m = wm * 64 + mi * 16 + r16;
        int o = ks_loc * 128 + quad * 32;
        int sw = (m & 15) << 4;
        const char* base = (const char*)AbufP[buf] + m * 256;
        float4 f0 = *(const float4*)(base + (o ^ sw));
        float4 f1 = *(const float4*)(base + ((o + 16) ^ sw));
        return bf16x8{(bf16_t)f0.x, (bf16_t)f0.y, (bf16_t)f0.z, (bf16_t)f0.w,
                      (bf16_t)f1.x, (bf16_t)f1.y, (bf16_t)f1.z, (bf16_t)f1.w};
      };

      #pragma unroll
      for (int kh = 0; kh < 4; ++kh) {
        if (kh < 3) STAGE((kh + 1) & 1, kh + 1);
        bf16x8 bfr[2][4];
        #pragma unroll
        for (int ks_loc = 0; ks_loc < 2; ++ks_loc)
          #pragma unroll
          for (int ni = 0; ni < 4; ++ni)
            bfr[ks_loc][ni] =
                *(const bf16x8*)(bpb[ni] + (kh * 2 + ks_loc) * 512);
        #pragma unroll
        for (int ks_loc = 0; ks_loc < 2; ++ks_loc) {
          bf16x8 afr[4];
          #pragma unroll
          for (int mi = 0; mi < 4; ++mi) afr[mi] = lda(kh & 1, mi, ks_loc);
          #pragma unroll
          for (int mi = 0; mi < 4; ++mi)
            #pragma unroll
            for (int ni = 0; ni < 4; ++ni)
              acc[mi][ni] = __builtin_amdgcn_mfma_f32_16x16x32_bf16(
                  afr[mi], bfr[ks_loc][ni], acc[mi][ni], 0, 0, 0);
        }
        __syncthreads();
      }
      #undef STAGE

      // epilogue: bias, bf16 round, stats, Cs transpose
      bf16_t* Cs = (bf16_t*)smem;  // [128][136] = 34.8 KB
      #pragma unroll
      for (int ni = 0; ni < 4; ++ni) {
        int ncol = wn * 64 + ni * 16 + r16;
        float psum = 0.f, psq = 0.f;
        #pragma unroll
        for (int mi = 0; mi < 4; ++mi) {
          #pragma unroll
          for (int r = 0; r < 4; ++r) {
            int mrow = wm * 64 + mi * 16 + quad * 4 + r;
            float val = acc[mi][ni][r] + bias_r[ni];
            bf16_t hbv = (bf16_t)val;
            Cs[mrow * 136 + ncol] = hbv;
            float hf = (float)hbv;  // stats from STORED value
            psum += hf; psq += hf * hf;
          }
        }
        atomicAdd(&s_sum[ncol], psum);
        atomicAdd(&s_sq[ncol], psq);
      }
      __syncthreads();

      bf16_t* hp = hbuf + (size_t)v * 256 + oh * 128;
      int col0 = (tid & 15) * 8;
      int rbase = tid >> 4;
      #pragma unroll
      for (int it = 0; it < 8; ++it) {
        int row = it * 16 + rbase;
        *(bf16x8*)(hp + (size_t)(b0 + row) * 16384 + col0) =
            *(const bf16x8*)&Cs[row * 136 + col0];
      }
      if (tid < 128) {
        atomicAdd(&g_sum[v * 256 + oh * 128 + tid], s_sum[tid]);
        atomicAdd(&g_sq[v * 256 + oh * 128 + tid], s_sq[tid]);
      }
    }
  }
  grid_barrier();

  // ======================= Phase 2: fold BN into affine (bf16) =============
  if (tid < 32) {
    int idx = blk * 32 + tid;  // 512*32 = 16384
    float s = g_sum[idx], q = g_sq[idx];
    float mean = s * (1.0f / 1024.0f);
    float var = fmaxf(q * (1.0f / 1024.0f) - mean * mean, 0.f);
    float rs = rsqrtf(var + EPS);
    float a = gamma[idx] * rs;
    a_bf[idx] = (bf16_t)a;
    c_bf[idx] = (bf16_t)(beta[idx] - mean * a);
  }
  grid_barrier();

  // ======================= Phase 3: mix + ReLU (2 b per block) =============
  {
    unsigned int* hsT = (unsigned int*)smem;  // 33792 B
    int w = wave;
    for (int t = 0; t < 2; ++t) {
      int b = blk + t * 512;
      const bf16_t* hb = hbuf + (size_t)b * 16384;
      __syncthreads();  // prev iteration's Lf reads complete

      bf16x8 afr[4][2];
      #pragma unroll
      for (int mi = 0; mi < 4; ++mi)
        #pragma unroll
        for (int ks = 0; ks < 2; ++ks)
          afr[mi][ks] = *(const bf16x8*)(adjB + (mi * 16 + r16) * 64 +
                                         ks * 32 + quad * 8);

      // stage hbn^T: hsT[o][v'] with v rotated by (o&56)
      #pragma unroll
      for (int i = 0; i < 4; ++i) {
        int idx2 = i * 256 + tid;
        int o8 = (idx2 & 31) * 8;
        int v0 = (idx2 >> 5) * 2;
        bf16x8 h0 = *(const bf16x8*)(hb + (size_t)v0 * 256 + o8);
        bf16x8 h1 = *(const bf16x8*)(hb + (size_t)(v0 + 1) * 256 + o8);
        bf16x8 a0 = *(const bf16x8*)(a_bf + v0 * 256 + o8);
        bf16x8 a1 = *(const bf16x8*)(a_bf + (v0 + 1) * 256 + o8);
        bf16x8 c0 = *(const bf16x8*)(c_bf + v0 * 256 + o8);
        bf16x8 c1 = *(const bf16x8*)(c_bf + (v0 + 1) * 256 + o8);
        #pragma unroll
        for (int j = 0; j < 8; ++j) {
          int o = o8 + j;
          unsigned short lo, hi;
          bf16_t d0 = (bf16_t)fmaf((float)h0[j], (float)a0[j], (float)c0[j]);
          bf16_t d1 = (bf16_t)fmaf((float)h1[j], (float)a1[j], (float)c1[j]);
          __builtin_memcpy(&lo, &d0, 2);
          __builtin_memcpy(&hi, &d1, 2);
          int vr = (v0 + (o & 56)) & 63;
          hsT[o * 33 + (vr >> 1)] = (unsigned int)lo | ((unsigned int)hi << 16);
        }
      }
      __syncthreads();

      floatx4 acc[4][4] = {};
      #pragma unroll
      for (int ks = 0; ks < 2; ++ks) {
        bf16x8 bfr[4];
        #pragma unroll
        for (int ni = 0; ni < 4; ++ni) {
          int o = (w * 4 + ni) * 16 + r16;
          int vbase = ks * 32 + quad * 8;
          int vr = (vbase + (o & 56)) & 63;
          const unsigned int* src = &hsT[o * 33 + (vr >> 1)];
          unsigned int tmp[4] = {src[0], src[1], src[2], src[3]};
          __builtin_memcpy(&bfr[ni], tmp, 16);
        }
        #pragma unroll
        for (int mi = 0; mi < 4; ++mi)
          #pragma unroll
          for (int ni = 0; ni < 4; ++ni)
            acc[mi][ni] = __builtin_amdgcn_mfma_f32_16x16x32_bf16(
                afr[mi][ks], bfr[ni], acc[mi][ni], 0, 0, 0);
      }

      // epilogue: relu via LDS f32 tile, full-line dwordx4 stores
      float* Lf = (float*)hsT;  // [32][260]
      float* ob = out + (size_t)b * 16384;
      #pragma unroll
      for (int half = 0; half < 2; ++half) {
        __syncthreads();
        #pragma unroll
        for (int mi2 = 0; mi2 < 2; ++mi2) {
          int mi = half * 2 + mi2;
          #pragma unroll
          for (int ni = 0; ni < 4; ++ni) {
            int o = (w * 4 + ni) * 16 + r16;
            #pragma unroll
            for (int r = 0; r < 4; ++r) {
              int ul = mi2 * 16 + quad * 4 + r;
              Lf[ul * 260 + o] = fmaxf(acc[mi][ni][r], 0.f);
            }
          }
        }
        __syncthreads();
        #pragma unroll
        for (int it = 0; it < 8; ++it) {
          int cid = it * 256 + tid;
          int row = cid >> 6, c4 = cid & 63;
          float4 val = *(const float4*)&Lf[row * 260 + c4 * 4];
          *(float4*)(ob + (size_t)(half * 32 + row) * 256 + c4 * 4) = val;
        }
      }
    }
  }
}

// ---------------------------------------------------------------------------
extern "C" void kernel_launch(void* const* d_in, const int* in_sizes, int n_in,
                              void* d_out, int out_size, void* d_ws, size_t ws_size,
                              hipStream_t stream) {
  const float* feat  = (const float*)d_in[0];  // [1024, 64, 256]
  const float* adj   = (const float*)d_in[1];  // [64, 64]
  const float* W     = (const float*)d_in[2];  // [64, 256, 256]
  const float* bias  = (const float*)d_in[3];  // [64, 256]
  const float* gamma = (const float*)d_in[4];  // [64, 256]
  const float* beta  = (const float*)d_in[5];  // [64, 256]
  float* out = (float*)d_out;                  // [1024, 64, 256]

  char* ws = (char*)d_ws;                      // needs ~41.3 MB
  bf16_t* Bp   = (bf16_t*)ws;                               // 8.4 MB packed W
  bf16_t* hbuf = (bf16_t*)(ws + (size_t)(9u << 20));        // 32 MB [B][V][O] bf16
  char* tail   = ws + (size_t)(41u << 20);
  float* g_sum = (float*)tail;                              // 64 KB
  float* g_sq  = (float*)(tail + 65536);                    // 64 KB
  bf16_t* a_bf = (bf16_t*)(tail + 2 * 65536);               // 32 KB
  bf16_t* c_bf = (bf16_t*)(tail + 2 * 65536 + 32768);       // 32 KB
  bf16_t* adjB = (bf16_t*)(tail + 3 * 65536);               //  8 KB

  fused_all<<<512, 256, 0, stream>>>(feat, adj, W, bias, gamma, beta, out,
                                     Bp, hbuf, g_sum, g_sq, a_bf, c_bf, adjB);
}

// Round 6
// 184.734 us; speedup vs baseline: 2.0278x; 2.0278x over previous
//
#include <hip/hip_runtime.h>

// Problem constants: B=1024, V=64, DIN=256, DOUT=256, fp32 in/out.
#define EPS 1e-5f

typedef __bf16 bf16_t;
typedef bf16_t bf16x4 __attribute__((ext_vector_type(4)));
typedef bf16_t bf16x8 __attribute__((ext_vector_type(8)));
typedef float  floatx4 __attribute__((ext_vector_type(4)));

// Fragment-pack layouts (verified, rounds 1-3):
//   A-frag chunk (mt, ks, lane): A[m = mt*16 + (lane&15)][k = ks*32 + (lane>>4)*8 + j]
//   B-frag chunk (nt, ks, lane): B[k = ks*32 + (lane>>4)*8 + j][n = nt*16 + (lane&15)]
//   C/D: col = lane&15, row = (lane>>4)*4 + reg

// ---------------------------------------------------------------------------
// K0a: Bp[v][nt16][ks8][lane][8] = bf16(W[v][k][n]); bx==512: adjB = bf16(adj);
//      bx==513: zero g_sum/g_sq (replaces hipMemsetAsync -> one fewer dispatch)
// ---------------------------------------------------------------------------
__global__ __launch_bounds__(256) void k0a_packW(
    const float* __restrict__ W, const float* __restrict__ adj,
    bf16_t* __restrict__ Bp, bf16_t* __restrict__ adjB,
    float* __restrict__ g_sum, float* __restrict__ g_sq) {
  int bx = blockIdx.x, tid = threadIdx.x;
  if (bx == 513) {  // zero the stats accumulators (16384 floats each)
    float4 z = {0.f, 0.f, 0.f, 0.f};
    #pragma unroll
    for (int i = 0; i < 16; ++i) {
      *(float4*)(g_sum + (i * 256 + tid) * 4) = z;
      *(float4*)(g_sq + (i * 256 + tid) * 4) = z;
    }
    return;
  }
  if (bx == 512) {  // adjB[u*64+v] = bf16(adj[u*64+v])
    int base = tid * 16;
    #pragma unroll
    for (int half = 0; half < 2; ++half) {
      float4 f0 = *(const float4*)(adj + base + half * 8);
      float4 f1 = *(const float4*)(adj + base + half * 8 + 4);
      bf16x8 d = {(bf16_t)f0.x, (bf16_t)f0.y, (bf16_t)f0.z, (bf16_t)f0.w,
                  (bf16_t)f1.x, (bf16_t)f1.y, (bf16_t)f1.z, (bf16_t)f1.w};
      *(bf16x8*)(adjB + base + half * 8) = d;
    }
    return;
  }
  int v = bx >> 3, ks = bx & 7, k0 = ks * 32;
  __shared__ __attribute__((aligned(16))) float Ls[32][260];
  const float* Wv = W + (size_t)v * 65536;
  #pragma unroll
  for (int it = 0; it < 8; ++it) {
    int idx = it * 256 + tid;
    int row = idx >> 6, c4 = idx & 63;
    *(float4*)&Ls[row][c4 * 4] = *(const float4*)(Wv + (size_t)(k0 + row) * 256 + c4 * 4);
  }
  __syncthreads();
  #pragma unroll
  for (int it = 0; it < 4; ++it) {
    int cc = it * 256 + tid;
    int nt = cc >> 6, lanec = cc & 63;
    int n = nt * 16 + (lanec & 15), kq = (lanec >> 4) * 8;
    bf16x8 d;
    #pragma unroll
    for (int j = 0; j < 8; ++j) d[j] = (bf16_t)Ls[kq + j][n];
    *(bf16x8*)(Bp + ((size_t)(v * 16 + nt) * 8 + ks) * 512 + lanec * 8) = d;
  }
}

// ---------------------------------------------------------------------------
// K1 (round 6): MINIMUM-INSTRUCTION k-loop.
//   Rounds 0/1/2/4 evidence: four different load structures all ~45-48us with
//   every pipe <12% busy; cycle models match measured durations only if the
//   kernels are instruction/issue-bound at a low effective core clock. So:
//   minimize instructions, not latency. This k1 has ZERO LDS, ZERO barriers:
//   - A: per-lane 32B contiguous reads of feat[b][v][k..k+7] (r3 layout),
//     depth-2 register prefetch; sched_barrier(0) between prefetch issue and
//     the MFMA block prevents the r3 compiler load-sinking (VGPR=40 tell).
//   - B: packed Bp fragments (L2-hot), same depth-2 prefetch.
//   - Epilogue: DIRECT global bf16 stores of h from acc (store-and-forget,
//     16-lane x 2B = 32B segments), stats via 2x shfl_xor (reduce over quad)
//     + global atomics from lane<16. No Cs transpose, no LDS atomics.
// ---------------------------------------------------------------------------
__global__ __launch_bounds__(256) void k1_gemm(
    const float* __restrict__ feat, const bf16_t* __restrict__ Bp,
    const float* __restrict__ bias, bf16_t* __restrict__ h,
    float* __restrict__ g_sum, float* __restrict__ g_sq) {
  int tid = threadIdx.x;
  int lane = tid & 63, wave = tid >> 6;   // 4 waves
  int wm = wave >> 1, wn = wave & 1;      // 2 (m=b) x 2 (n=o)
  int r16 = lane & 15, quad = lane >> 4;
  int v = blockIdx.x, oh = blockIdx.y, b0 = blockIdx.z * 128;

  // ---- A source: feat[b][v][k], per-lane 32B contiguous ------------------
  const float* fb[4];
  #pragma unroll
  for (int mi = 0; mi < 4; ++mi)
    fb[mi] = feat + (size_t)(b0 + wm * 64 + mi * 16 + r16) * 16384 + v * 256 + quad * 8;

  // ---- B source: packed Bp fragments (L2-hot) ----------------------------
  const bf16_t* bpb[4];
  #pragma unroll
  for (int ni = 0; ni < 4; ++ni) {
    int nt = oh * 8 + wn * 4 + ni;
    bpb[ni] = Bp + ((size_t)(v * 16 + nt) * 8) * 512 + lane * 8;
  }

  floatx4 acc[4][4] = {};

  float4 a0c[4], a1c[4], a0n[4], a1n[4];
  bf16x8 bc[4], bn[4];
  #pragma unroll
  for (int mi = 0; mi < 4; ++mi) {
    a0c[mi] = *(const float4*)(fb[mi]);
    a1c[mi] = *(const float4*)(fb[mi] + 4);
  }
  #pragma unroll
  for (int ni = 0; ni < 4; ++ni) bc[ni] = *(const bf16x8*)bpb[ni];

  #pragma unroll
  for (int ks = 0; ks < 8; ++ks) {
    if (ks < 7) {
      #pragma unroll
      for (int mi = 0; mi < 4; ++mi) {
        a0n[mi] = *(const float4*)(fb[mi] + (ks + 1) * 32);
        a1n[mi] = *(const float4*)(fb[mi] + (ks + 1) * 32 + 4);
      }
      #pragma unroll
      for (int ni = 0; ni < 4; ++ni) bn[ni] = *(const bf16x8*)(bpb[ni] + (ks + 1) * 512);
      // keep prefetch ABOVE the MFMA block (r3: compiler sank it -> serial)
      __builtin_amdgcn_sched_barrier(0);
    }
    bf16x8 ac[4];
    #pragma unroll
    for (int mi = 0; mi < 4; ++mi)
      ac[mi] = bf16x8{(bf16_t)a0c[mi].x, (bf16_t)a0c[mi].y, (bf16_t)a0c[mi].z, (bf16_t)a0c[mi].w,
                      (bf16_t)a1c[mi].x, (bf16_t)a1c[mi].y, (bf16_t)a1c[mi].z, (bf16_t)a1c[mi].w};
    #pragma unroll
    for (int mi = 0; mi < 4; ++mi)
      #pragma unroll
      for (int ni = 0; ni < 4; ++ni)
        acc[mi][ni] = __builtin_amdgcn_mfma_f32_16x16x32_bf16(
            ac[mi], bc[ni], acc[mi][ni], 0, 0, 0);
    if (ks < 7) {
      #pragma unroll
      for (int mi = 0; mi < 4; ++mi) { a0c[mi] = a0n[mi]; a1c[mi] = a1n[mi]; }
      #pragma unroll
      for (int ni = 0; ni < 4; ++ni) bc[ni] = bn[ni];
    }
  }

  // ---- epilogue: bias, bf16 round, DIRECT h stores, shuffle stats --------
  float bias_r[4];
  #pragma unroll
  for (int ni = 0; ni < 4; ++ni)
    bias_r[ni] = bias[v * 256 + oh * 128 + wn * 64 + ni * 16 + r16];

  bf16_t* hp = h + (size_t)v * 256 + oh * 128;
  float psum[4], psq[4];
  #pragma unroll
  for (int ni = 0; ni < 4; ++ni) { psum[ni] = 0.f; psq[ni] = 0.f; }

  #pragma unroll
  for (int ni = 0; ni < 4; ++ni) {
    int ocol = wn * 64 + ni * 16 + r16;
    #pragma unroll
    for (int mi = 0; mi < 4; ++mi) {
      #pragma unroll
      for (int r = 0; r < 4; ++r) {
        int mrow = b0 + wm * 64 + mi * 16 + quad * 4 + r;
        float val = acc[mi][ni][r] + bias_r[ni];
        bf16_t hbv = (bf16_t)val;
        hp[(size_t)mrow * 16384 + ocol] = hbv;
        float hf = (float)hbv;  // stats from STORED value (self-consistent BN)
        psum[ni] += hf; psq[ni] += hf * hf;
      }
    }
  }
  // reduce over quad (lanes differing in bits 4,5); r16 (col) preserved
  #pragma unroll
  for (int ni = 0; ni < 4; ++ni) {
    psum[ni] += __shfl_xor(psum[ni], 16);
    psq[ni]  += __shfl_xor(psq[ni], 16);
    psum[ni] += __shfl_xor(psum[ni], 32);
    psq[ni]  += __shfl_xor(psq[ni], 32);
  }
  if (quad == 0) {
    #pragma unroll
    for (int ni = 0; ni < 4; ++ni) {
      int o = v * 256 + oh * 128 + wn * 64 + ni * 16 + r16;
      atomicAdd(&g_sum[o], psum[ni]);
      atomicAdd(&g_sq[o], psq[ni]);
    }
  }
}

// ---------------------------------------------------------------------------
// K2: fold BN into per-(v,o) affine, emitted as BF16 (halves k4 param traffic)
// ---------------------------------------------------------------------------
__global__ __launch_bounds__(256) void k2_stats(
    const float* __restrict__ g_sum, const float* __restrict__ g_sq,
    const float* __restrict__ gamma, const float* __restrict__ beta,
    bf16_t* __restrict__ a_bf, bf16_t* __restrict__ c_bf) {
  int idx = blockIdx.x * 256 + threadIdx.x;
  float s = g_sum[idx], q = g_sq[idx];
  float mean = s * (1.0f / 1024.0f);
  float var = fmaxf(q * (1.0f / 1024.0f) - mean * mean, 0.f);
  float rs = rsqrtf(var + EPS);
  float a = gamma[idx] * rs;
  a_bf[idx] = (bf16_t)a;
  c_bf[idx] = (bf16_t)(beta[idx] - mean * a);
}

// ---------------------------------------------------------------------------
// K4: out[b,u,o] = relu(sum_v adj[u,v] * (a*h+c)[b,v,o]) via bf16 MFMA.
//     One block per b. Stage hbn transposed in LDS (v-rotation swizzle), mix
//     with MFMA (A=adjB L1-hot), then re-stage out through LDS (reusing hsT)
//     for FULL-LINE dwordx4 stores.
// ---------------------------------------------------------------------------
__global__ __launch_bounds__(256) void k4_mix(
    const bf16_t* __restrict__ h, const bf16_t* __restrict__ adjB,
    const bf16_t* __restrict__ a_bf, const bf16_t* __restrict__ c_bf,
    float* __restrict__ out) {
  __shared__ unsigned int hsT[256 * 33];  // 33792B; reused as f32 [32][260] later
  int tid = threadIdx.x;
  int lane = tid & 63, w = tid >> 6;
  int r16 = lane & 15, quad = lane >> 4;
  int b = blockIdx.x;
  const bf16_t* hb = h + (size_t)b * 16384;

  // A-fragments (adjB 8KB, L1-hot): frag (mi, ks): u=mi*16+r16, k=ks*32+quad*8
  bf16x8 afr[4][2];
  #pragma unroll
  for (int mi = 0; mi < 4; ++mi)
    #pragma unroll
    for (int ks = 0; ks < 2; ++ks)
      afr[mi][ks] = *(const bf16x8*)(adjB + (mi * 16 + r16) * 64 + ks * 32 + quad * 8);

  // stage hbn^T: hsT[o][v'] with v rotated by (o&56) (breaks 8-way wr conflicts)
  #pragma unroll
  for (int i = 0; i < 4; ++i) {
    int idx2 = i * 256 + tid;
    int o8 = (idx2 & 31) * 8;
    int v0 = (idx2 >> 5) * 2;
    bf16x8 h0 = *(const bf16x8*)(hb + (size_t)v0 * 256 + o8);
    bf16x8 h1 = *(const bf16x8*)(hb + (size_t)(v0 + 1) * 256 + o8);
    bf16x8 a0 = *(const bf16x8*)(a_bf + v0 * 256 + o8);
    bf16x8 a1 = *(const bf16x8*)(a_bf + (v0 + 1) * 256 + o8);
    bf16x8 c0 = *(const bf16x8*)(c_bf + v0 * 256 + o8);
    bf16x8 c1 = *(const bf16x8*)(c_bf + (v0 + 1) * 256 + o8);
    #pragma unroll
    for (int j = 0; j < 8; ++j) {
      int o = o8 + j;
      unsigned short lo, hi;
      bf16_t d0 = (bf16_t)fmaf((float)h0[j], (float)a0[j], (float)c0[j]);
      bf16_t d1 = (bf16_t)fmaf((float)h1[j], (float)a1[j], (float)c1[j]);
      __builtin_memcpy(&lo, &d0, 2);
      __builtin_memcpy(&hi, &d1, 2);
      int vr = (v0 + (o & 56)) & 63;
      hsT[o * 33 + (vr >> 1)] = (unsigned int)lo | ((unsigned int)hi << 16);
    }
  }
  __syncthreads();

  // mix: wave w -> o-range w*64..+64 (nt=w*4+ni), all 4 u-tiles, 2 ksteps
  floatx4 acc[4][4] = {};
  #pragma unroll
  for (int ks = 0; ks < 2; ++ks) {
    bf16x8 bfr[4];
    #pragma unroll
    for (int ni = 0; ni < 4; ++ni) {
      int o = (w * 4 + ni) * 16 + r16;
      int vbase = ks * 32 + quad * 8;
      int vr = (vbase + (o & 56)) & 63;
      const unsigned int* src = &hsT[o * 33 + (vr >> 1)];
      unsigned int tmp[4] = {src[0], src[1], src[2], src[3]};
      __builtin_memcpy(&bfr[ni], tmp, 16);
    }
    #pragma unroll
    for (int mi = 0; mi < 4; ++mi)
      #pragma unroll
      for (int ni = 0; ni < 4; ++ni)
        acc[mi][ni] = __builtin_amdgcn_mfma_f32_16x16x32_bf16(
            afr[mi][ks], bfr[ni], acc[mi][ni], 0, 0, 0);
  }

  // epilogue: relu into LDS f32 tile (u-halves), then full-line dwordx4 stores
  float* Lf = (float*)hsT;  // [32][260] = 33280B fits in hsT
  float* ob = out + (size_t)b * 16384;
  #pragma unroll
  for (int half = 0; half < 2; ++half) {
    __syncthreads();  // previous use of hsT/Lf complete
    #pragma unroll
    for (int mi2 = 0; mi2 < 2; ++mi2) {
      int mi = half * 2 + mi2;
      #pragma unroll
      for (int ni = 0; ni < 4; ++ni) {
        int o = (w * 4 + ni) * 16 + r16;
        #pragma unroll
        for (int r = 0; r < 4; ++r) {
          int ul = mi2 * 16 + quad * 4 + r;  // u-local 0..31
          Lf[ul * 260 + o] = fmaxf(acc[mi][ni][r], 0.f);
        }
      }
    }
    __syncthreads();
    // 32 rows x 256 o fp32 -> one full 1KB row per wave-instr
    #pragma unroll
    for (int it = 0; it < 8; ++it) {
      int cid = it * 256 + tid;
      int row = cid >> 6, c4 = cid & 63;
      float4 val = *(const float4*)&Lf[row * 260 + c4 * 4];
      *(float4*)(ob + (size_t)(half * 32 + row) * 256 + c4 * 4) = val;
    }
  }
}

// ---------------------------------------------------------------------------
extern "C" void kernel_launch(void* const* d_in, const int* in_sizes, int n_in,
                              void* d_out, int out_size, void* d_ws, size_t ws_size,
                              hipStream_t stream) {
  const float* feat  = (const float*)d_in[0];  // [1024, 64, 256]
  const float* adj   = (const float*)d_in[1];  // [64, 64]
  const float* W     = (const float*)d_in[2];  // [64, 256, 256]
  const float* bias  = (const float*)d_in[3];  // [64, 256]
  const float* gamma = (const float*)d_in[4];  // [64, 256]
  const float* beta  = (const float*)d_in[5];  // [64, 256]
  float* out = (float*)d_out;                  // [1024, 64, 256]

  char* ws = (char*)d_ws;                      // needs ~41.3 MB
  bf16_t* Bp   = (bf16_t*)ws;                               // 8.4 MB packed W
  bf16_t* hbuf = (bf16_t*)(ws + (size_t)(9u << 20));        // 32 MB [B][V][O] bf16
  char* tail   = ws + (size_t)(41u << 20);
  float* g_sum = (float*)tail;                              // 64 KB
  float* g_sq  = (float*)(tail + 65536);                    // 64 KB
  bf16_t* a_bf = (bf16_t*)(tail + 2 * 65536);               // 32 KB
  bf16_t* c_bf = (bf16_t*)(tail + 2 * 65536 + 32768);       // 32 KB
  bf16_t* adjB = (bf16_t*)(tail + 3 * 65536);               //  8 KB

  k0a_packW<<<514, 256, 0, stream>>>(W, adj, Bp, adjB, g_sum, g_sq);
  k1_gemm<<<dim3(64, 2, 8), 256, 0, stream>>>(feat, Bp, bias, hbuf, g_sum, g_sq);
  k2_stats<<<64, 256, 0, stream>>>(g_sum, g_sq, gamma, beta, a_bf, c_bf);
  k4_mix<<<1024, 256, 0, stream>>>(hbuf, adjB, a_bf, c_bf, out);
}

// Round 7
// 173.919 us; speedup vs baseline: 2.1540x; 1.0622x over previous
//
#include <hip/hip_runtime.h>

// Problem constants: B=1024, V=64, DIN=256, DOUT=256, fp32 in/out.
#define EPS 1e-5f

typedef __bf16 bf16_t;
typedef bf16_t bf16x4 __attribute__((ext_vector_type(4)));
typedef bf16_t bf16x8 __attribute__((ext_vector_type(8)));
typedef float  floatx4 __attribute__((ext_vector_type(4)));

// Fragment-pack layouts (verified):
//   A-frag chunk (mt, ks, lane): A[m = mt*16 + (lane&15)][k = ks*32 + (lane>>4)*8 + j]
//   B-frag chunk (nt, ks, lane): B[k = ks*32 + (lane>>4)*8 + j][n = nt*16 + (lane&15)]
//   C/D: col = lane&15, row = (lane>>4)*4 + reg
//
// Round-7 calibration: MfmaUtil-implied core clock ~800 MHz across r1/r2/r3/
// r5/r6 (5 structures) -> cycles are 3x nominal cost; ~89us fixed per-graph
// harness cost (poison fills). Controllable budget = kernel cycle counts.

// ---------------------------------------------------------------------------
// K0a: Bp[v][nt16][ks8][lane][8] = bf16(W[v][k][n]); bx==512: adjB = bf16(adj);
//      bx==513: zero g_sum/g_sq
// ---------------------------------------------------------------------------
__global__ __launch_bounds__(256) void k0a_packW(
    const float* __restrict__ W, const float* __restrict__ adj,
    bf16_t* __restrict__ Bp, bf16_t* __restrict__ adjB,
    float* __restrict__ g_sum, float* __restrict__ g_sq) {
  int bx = blockIdx.x, tid = threadIdx.x;
  if (bx == 513) {  // zero the stats accumulators (16384 floats each)
    float4 z = {0.f, 0.f, 0.f, 0.f};
    #pragma unroll
    for (int i = 0; i < 16; ++i) {
      *(float4*)(g_sum + (i * 256 + tid) * 4) = z;
      *(float4*)(g_sq + (i * 256 + tid) * 4) = z;
    }
    return;
  }
  if (bx == 512) {  // adjB[u*64+v] = bf16(adj[u*64+v])
    int base = tid * 16;
    #pragma unroll
    for (int half = 0; half < 2; ++half) {
      float4 f0 = *(const float4*)(adj + base + half * 8);
      float4 f1 = *(const float4*)(adj + base + half * 8 + 4);
      bf16x8 d = {(bf16_t)f0.x, (bf16_t)f0.y, (bf16_t)f0.z, (bf16_t)f0.w,
                  (bf16_t)f1.x, (bf16_t)f1.y, (bf16_t)f1.z, (bf16_t)f1.w};
      *(bf16x8*)(adjB + base + half * 8) = d;
    }
    return;
  }
  int v = bx >> 3, ks = bx & 7, k0 = ks * 32;
  __shared__ __attribute__((aligned(16))) float Ls[32][260];
  const float* Wv = W + (size_t)v * 65536;
  #pragma unroll
  for (int it = 0; it < 8; ++it) {
    int idx = it * 256 + tid;
    int row = idx >> 6, c4 = idx & 63;
    *(float4*)&Ls[row][c4 * 4] = *(const float4*)(Wv + (size_t)(k0 + row) * 256 + c4 * 4);
  }
  __syncthreads();
  #pragma unroll
  for (int it = 0; it < 4; ++it) {
    int cc = it * 256 + tid;
    int nt = cc >> 6, lanec = cc & 63;
    int n = nt * 16 + (lanec & 15), kq = (lanec >> 4) * 8;
    bf16x8 d;
    #pragma unroll
    for (int j = 0; j < 8; ++j) d[j] = (bf16_t)Ls[kq + j][n];
    *(bf16x8*)(Bp + ((size_t)(v * 16 + nt) * 8 + ks) * 512 + lanec * 8) = d;
  }
}

// ---------------------------------------------------------------------------
// K1 (round 7): 64b x 256o tile, feat staged ONCE, 4 independent blocks/CU.
//   r1 (best, 44.6us) staged feat twice (oh split) with 2 blocks/CU; r2's
//   single-read used one 512-thr barrier-locked block (no independent
//   overlap). This combines: single feat read (halved staging volume), 34KB
//   LDS -> 4 independent blocks/CU whose phases desynchronize, and r1's
//   proven per-wave k-loop (LDS A-frags XOR-swizzled, Bp depth-1 reg
//   prefetch). Wave wn owns o-slice wn*64..+64; acc[4][4] over 64b x 64o.
// ---------------------------------------------------------------------------
__global__ __launch_bounds__(256, 4) void k1_gemm(
    const float* __restrict__ feat, const bf16_t* __restrict__ Bp,
    const float* __restrict__ bias, bf16_t* __restrict__ h,
    float* __restrict__ g_sum, float* __restrict__ g_sq) {
  // 32 KB: A-tile bf16 [64 m][256 k], byte ^= (m&7)<<4 swizzle.
  // Reused after the k-loop as Cs [64][264] bf16 (33.8 KB).
  __shared__ __attribute__((aligned(16))) bf16_t As[64 * 264];
  __shared__ float s_sum[256], s_sq[256];

  int tid = threadIdx.x;
  int lane = tid & 63, wn = tid >> 6;     // 4 waves, each owns o-slice wn*64
  int r16 = lane & 15, quad = lane >> 4;
  int v = blockIdx.x, b0 = blockIdx.y * 64;

  s_sum[tid] = 0.f; s_sq[tid] = 0.f;

  // ---- stage A once: As[m][k] = bf16(feat[b0+m][v][k]), swizzled ---------
  const float* fv = feat + (size_t)b0 * 16384 + v * 256;
  #pragma unroll
  for (int it = 0; it < 8; ++it) {
    int idx = it * 256 + tid;            // 0..2047 (64 rows x 32 chunks)
    int m = idx >> 5, k8 = (idx & 31) * 8;
    float4 f0 = *(const float4*)(fv + (size_t)m * 16384 + k8);
    float4 f1 = *(const float4*)(fv + (size_t)m * 16384 + k8 + 4);
    bf16x8 d = {(bf16_t)f0.x, (bf16_t)f0.y, (bf16_t)f0.z, (bf16_t)f0.w,
                (bf16_t)f1.x, (bf16_t)f1.y, (bf16_t)f1.z, (bf16_t)f1.w};
    int byte = (m * 512 + k8 * 2) ^ ((m & 7) << 4);
    *(bf16x8*)((char*)As + byte) = d;
  }
  __syncthreads();

  // ---- k-loop: A from swizzled LDS, B from packed global (r1 shape) ------
  floatx4 acc[4][4] = {};

  const bf16_t* bpb[4];
  #pragma unroll
  for (int ni = 0; ni < 4; ++ni) {
    int nt = wn * 4 + ni;                // 0..15, full o=256
    bpb[ni] = Bp + ((size_t)(v * 16 + nt) * 8) * 512 + lane * 8;
  }

  auto lda = [&](int mi, int ks) -> bf16x8 {
    int m = mi * 16 + r16;               // 0..63
    int byte = (m * 512 + ks * 64 + quad * 16) ^ ((m & 7) << 4);
    return *(const bf16x8*)((const char*)As + byte);
  };

  bf16x8 ac[4], bc[4], an[4], bn[4];
  #pragma unroll
  for (int mi = 0; mi < 4; ++mi) ac[mi] = lda(mi, 0);
  #pragma unroll
  for (int ni = 0; ni < 4; ++ni) bc[ni] = *(const bf16x8*)bpb[ni];

  #pragma unroll
  for (int ks = 0; ks < 8; ++ks) {
    if (ks < 7) {
      #pragma unroll
      for (int mi = 0; mi < 4; ++mi) an[mi] = lda(mi, ks + 1);
      #pragma unroll
      for (int ni = 0; ni < 4; ++ni) bn[ni] = *(const bf16x8*)(bpb[ni] + (ks + 1) * 512);
    }
    #pragma unroll
    for (int mi = 0; mi < 4; ++mi)
      #pragma unroll
      for (int ni = 0; ni < 4; ++ni)
        acc[mi][ni] = __builtin_amdgcn_mfma_f32_16x16x32_bf16(
            ac[mi], bc[ni], acc[mi][ni], 0, 0, 0);
    if (ks < 7) {
      #pragma unroll
      for (int mi = 0; mi < 4; ++mi) ac[mi] = an[mi];
      #pragma unroll
      for (int ni = 0; ni < 4; ++ni) bc[ni] = bn[ni];
    }
  }

  __syncthreads();  // all A-LDS reads done; safe to reuse as Cs

  bf16_t* Cs = As;  // [64][264] bf16

  float bias_r[4];
  #pragma unroll
  for (int ni = 0; ni < 4; ++ni)
    bias_r[ni] = bias[v * 256 + wn * 64 + ni * 16 + r16];

  #pragma unroll
  for (int ni = 0; ni < 4; ++ni) {
    int ncol = wn * 64 + ni * 16 + r16;  // o 0..255
    float psum = 0.f, psq = 0.f;
    #pragma unroll
    for (int mi = 0; mi < 4; ++mi) {
      #pragma unroll
      for (int r = 0; r < 4; ++r) {
        int mrow = mi * 16 + quad * 4 + r;  // b-local 0..63
        float val = acc[mi][ni][r] + bias_r[ni];
        bf16_t hbv = (bf16_t)val;
        Cs[mrow * 264 + ncol] = hbv;
        float hf = (float)hbv;  // stats from STORED value (self-consistent BN)
        psum += hf; psq += hf * hf;
      }
    }
    atomicAdd(&s_sum[ncol], psum);
    atomicAdd(&s_sq[ncol], psq);
  }
  __syncthreads();

  // h-store: 32 lanes x 16B = 512B contiguous per row
  bf16_t* hp = h + (size_t)v * 256;
  int col0 = (tid & 31) * 8;
  int rbase = tid >> 5;  // 0..7
  #pragma unroll
  for (int it = 0; it < 8; ++it) {
    int row = it * 8 + rbase;
    *(bf16x8*)(hp + (size_t)(b0 + row) * 16384 + col0) = *(const bf16x8*)&Cs[row * 264 + col0];
  }
  atomicAdd(&g_sum[v * 256 + tid], s_sum[tid]);
  atomicAdd(&g_sq[v * 256 + tid], s_sq[tid]);
}

// ---------------------------------------------------------------------------
// K2: fold BN into per-(v,o) affine, emitted as FP32 (r7: kills 4 cvts/elem
//     in k4's hot stage loop; 128KB total, L2-resident)
// ---------------------------------------------------------------------------
__global__ __launch_bounds__(256) void k2_stats(
    const float* __restrict__ g_sum, const float* __restrict__ g_sq,
    const float* __restrict__ gamma, const float* __restrict__ beta,
    float* __restrict__ a_f, float* __restrict__ c_f) {
  int idx = blockIdx.x * 256 + threadIdx.x;
  float s = g_sum[idx], q = g_sq[idx];
  float mean = s * (1.0f / 1024.0f);
  float var = fmaxf(q * (1.0f / 1024.0f) - mean * mean, 0.f);
  float rs = rsqrtf(var + EPS);
  float a = gamma[idx] * rs;
  a_f[idx] = a;
  c_f[idx] = beta[idx] - mean * a;
}

// ---------------------------------------------------------------------------
// K4 (round 7): 2 b per block (grid 512), f32 a/c, lean pack.
//   Stage loop was ~13 VALU/elem (4 of them bf16->f32 cvts of a,c); with f32
//   a/c it's ~6/elem and the two bf16 casts per (v0,v1) pair fuse into
//   v_cvt_pk_bf16_f32. adjB A-fragments loaded once per block (amortized
//   across both b). Everything else is the verified r0 structure.
// ---------------------------------------------------------------------------
__global__ __launch_bounds__(256) void k4_mix(
    const bf16_t* __restrict__ h, const bf16_t* __restrict__ adjB,
    const float* __restrict__ a_f, const float* __restrict__ c_f,
    float* __restrict__ out) {
  __shared__ unsigned int hsT[256 * 33];  // 33792B; reused as f32 [32][260] later
  int tid = threadIdx.x;
  int lane = tid & 63, w = tid >> 6;
  int r16 = lane & 15, quad = lane >> 4;

  // A-fragments (adjB 8KB, L1-hot): frag (mi, ks): u=mi*16+r16, k=ks*32+quad*8
  bf16x8 afr[4][2];
  #pragma unroll
  for (int mi = 0; mi < 4; ++mi)
    #pragma unroll
    for (int ks = 0; ks < 2; ++ks)
      afr[mi][ks] = *(const bf16x8*)(adjB + (mi * 16 + r16) * 64 + ks * 32 + quad * 8);

  for (int t = 0; t < 2; ++t) {
    int b = blockIdx.x * 2 + t;
    const bf16_t* hb = h + (size_t)b * 16384;
    if (t) __syncthreads();  // previous iteration's Lf reads complete

    // stage hbn^T: hsT[o][v'] with v rotated by (o&56) (breaks wr conflicts)
    #pragma unroll
    for (int i = 0; i < 4; ++i) {
      int idx2 = i * 256 + tid;
      int o8 = (idx2 & 31) * 8;
      int v0 = (idx2 >> 5) * 2;
      bf16x8 h0 = *(const bf16x8*)(hb + (size_t)v0 * 256 + o8);
      bf16x8 h1 = *(const bf16x8*)(hb + (size_t)(v0 + 1) * 256 + o8);
      float av0[8], av1[8], cv0[8], cv1[8];
      *(float4*)&av0[0] = *(const float4*)(a_f + v0 * 256 + o8);
      *(float4*)&av0[4] = *(const float4*)(a_f + v0 * 256 + o8 + 4);
      *(float4*)&av1[0] = *(const float4*)(a_f + (v0 + 1) * 256 + o8);
      *(float4*)&av1[4] = *(const float4*)(a_f + (v0 + 1) * 256 + o8 + 4);
      *(float4*)&cv0[0] = *(const float4*)(c_f + v0 * 256 + o8);
      *(float4*)&cv0[4] = *(const float4*)(c_f + v0 * 256 + o8 + 4);
      *(float4*)&cv1[0] = *(const float4*)(c_f + (v0 + 1) * 256 + o8);
      *(float4*)&cv1[4] = *(const float4*)(c_f + (v0 + 1) * 256 + o8 + 4);
      #pragma unroll
      for (int j = 0; j < 8; ++j) {
        int o = o8 + j;
        unsigned short lo, hi;
        bf16_t d0 = (bf16_t)fmaf((float)h0[j], av0[j], cv0[j]);
        bf16_t d1 = (bf16_t)fmaf((float)h1[j], av1[j], cv1[j]);
        __builtin_memcpy(&lo, &d0, 2);
        __builtin_memcpy(&hi, &d1, 2);
        int vr = (v0 + (o & 56)) & 63;
        hsT[o * 33 + (vr >> 1)] = (unsigned int)lo | ((unsigned int)hi << 16);
      }
    }
    __syncthreads();

    // mix: wave w -> o-range w*64..+64 (nt=w*4+ni), all 4 u-tiles, 2 ksteps
    floatx4 acc[4][4] = {};
    #pragma unroll
    for (int ks = 0; ks < 2; ++ks) {
      bf16x8 bfr[4];
      #pragma unroll
      for (int ni = 0; ni < 4; ++ni) {
        int o = (w * 4 + ni) * 16 + r16;
        int vbase = ks * 32 + quad * 8;
        int vr = (vbase + (o & 56)) & 63;
        const unsigned int* src = &hsT[o * 33 + (vr >> 1)];
        unsigned int tmp[4] = {src[0], src[1], src[2], src[3]};
        __builtin_memcpy(&bfr[ni], tmp, 16);
      }
      #pragma unroll
      for (int mi = 0; mi < 4; ++mi)
        #pragma unroll
        for (int ni = 0; ni < 4; ++ni)
          acc[mi][ni] = __builtin_amdgcn_mfma_f32_16x16x32_bf16(
              afr[mi][ks], bfr[ni], acc[mi][ni], 0, 0, 0);
    }

    // epilogue: relu into LDS f32 tile (u-halves), then full-line stores
    float* Lf = (float*)hsT;  // [32][260] = 33280B fits in hsT
    float* ob = out + (size_t)b * 16384;
    #pragma unroll
    for (int half = 0; half < 2; ++half) {
      __syncthreads();  // previous use of hsT/Lf complete
      #pragma unroll
      for (int mi2 = 0; mi2 < 2; ++mi2) {
        int mi = half * 2 + mi2;
        #pragma unroll
        for (int ni = 0; ni < 4; ++ni) {
          int o = (w * 4 + ni) * 16 + r16;
          #pragma unroll
          for (int r = 0; r < 4; ++r) {
            int ul = mi2 * 16 + quad * 4 + r;  // u-local 0..31
            Lf[ul * 260 + o] = fmaxf(acc[mi][ni][r], 0.f);
          }
        }
      }
      __syncthreads();
      // 32 rows x 256 o fp32 -> one full 1KB row per wave-instr
      #pragma unroll
      for (int it = 0; it < 8; ++it) {
        int cid = it * 256 + tid;
        int row = cid >> 6, c4 = cid & 63;
        float4 val = *(const float4*)&Lf[row * 260 + c4 * 4];
        *(float4*)(ob + (size_t)(half * 32 + row) * 256 + c4 * 4) = val;
      }
    }
  }
}

// ---------------------------------------------------------------------------
extern "C" void kernel_launch(void* const* d_in, const int* in_sizes, int n_in,
                              void* d_out, int out_size, void* d_ws, size_t ws_size,
                              hipStream_t stream) {
  const float* feat  = (const float*)d_in[0];  // [1024, 64, 256]
  const float* adj   = (const float*)d_in[1];  // [64, 64]
  const float* W     = (const float*)d_in[2];  // [64, 256, 256]
  const float* bias  = (const float*)d_in[3];  // [64, 256]
  const float* gamma = (const float*)d_in[4];  // [64, 256]
  const float* beta  = (const float*)d_in[5];  // [64, 256]
  float* out = (float*)d_out;                  // [1024, 64, 256]

  char* ws = (char*)d_ws;                      // needs ~41.6 MB
  bf16_t* Bp   = (bf16_t*)ws;                               // 8.4 MB packed W
  bf16_t* hbuf = (bf16_t*)(ws + (size_t)(9u << 20));        // 32 MB [B][V][O] bf16
  char* tail   = ws + (size_t)(41u << 20);
  float* g_sum = (float*)tail;                              // 64 KB
  float* g_sq  = (float*)(tail + 65536);                    // 64 KB
  float* a_f   = (float*)(tail + 2 * 65536);                // 64 KB (fp32 now)
  float* c_f   = (float*)(tail + 3 * 65536);                // 64 KB (fp32 now)
  bf16_t* adjB = (bf16_t*)(tail + 4 * 65536);               //  8 KB

  k0a_packW<<<514, 256, 0, stream>>>(W, adj, Bp, adjB, g_sum, g_sq);
  k1_gemm<<<dim3(64, 16), 256, 0, stream>>>(feat, Bp, bias, hbuf, g_sum, g_sq);
  k2_stats<<<64, 256, 0, stream>>>(g_sum, g_sq, gamma, beta, a_f, c_f);
  k4_mix<<<512, 256, 0, stream>>>(hbuf, adjB, a_f, c_f, out);
}